// Round 7
// baseline (89.849 us; speedup 1.0000x reference)
//
#include <hip/hip_runtime.h>

// mask[b, i, j] = (i < len_q[b]) & (j < len_k[b]);  out is int32 (0 / 1)
// B=32, SEQ=2048  ->  out_size = 32*2048*2048 = 134,217,728 ints (512 MiB)
//
// Fire-and-forget store stream (R6 structure, won 93->84us), with 512-thread
// blocks to halve dispatch packet count: 65536 blocks x 512 threads,
// exactly ONE int4 store per thread.

constexpr int SEQ = 2048;
constexpr int THREADS = 512;

typedef int int4v __attribute__((ext_vector_type(4)));

__global__ __launch_bounds__(512) void padmask_kernel(
        const int* __restrict__ len_q,
        const int* __restrict__ len_k,
        int* __restrict__ out) {
    const int idx = blockIdx.x * THREADS + threadIdx.x;   // int4 index, 0..2^25-1

    const int b = blockIdx.x >> 11;          // 2048 blocks per batch sample
    const int i = (idx >> 9) & (SEQ - 1);    // row (512 int4 per row)
    const int j = (idx & 511) << 2;          // element column of lane's .x

    const int lq = len_q[b];
    const int lk = len_k[b];
    const bool qv = (i < lq);

    int4v v;
    v.x = (qv && (j + 0) < lk) ? 1 : 0;
    v.y = (qv && (j + 1) < lk) ? 1 : 0;
    v.z = (qv && (j + 2) < lk) ? 1 : 0;
    v.w = (qv && (j + 3) < lk) ? 1 : 0;
    reinterpret_cast<int4v*>(out)[idx] = v;
}

extern "C" void kernel_launch(void* const* d_in, const int* in_sizes, int n_in,
                              void* d_out, int out_size, void* d_ws, size_t ws_size,
                              hipStream_t stream) {
    const int* len_q = (const int*)d_in[0];
    const int* len_k = (const int*)d_in[1];
    int* out = (int*)d_out;

    const int n_int4 = out_size / 4;                 // 33,554,432
    const int blocks = n_int4 / THREADS;             // 65,536

    padmask_kernel<<<blocks, THREADS, 0, stream>>>(len_q, len_k, out);
}